// Round 1
// baseline (761.489 us; speedup 1.0000x reference)
//
#include <hip/hip_runtime.h>
#include <hip/hip_bf16.h>
#include <stdint.h>

#define B_   4
#define L_   2048
#define D_   1024
#define H_   16
#define DH_  64
#define DFF_ 4096
#define EPS_ 1e-5f

typedef short s16x8 __attribute__((ext_vector_type(8)));
typedef short s16x4 __attribute__((ext_vector_type(4)));
typedef float f32x4 __attribute__((ext_vector_type(4)));

static __device__ __forceinline__ short f2bf(float f) {
    return __builtin_bit_cast(short, __float2bfloat16(f));
}

static __device__ __forceinline__ void gload_lds16(const void* g, void* l) {
    __builtin_amdgcn_global_load_lds(
        (const __attribute__((address_space(1))) uint32_t*)g,
        (__attribute__((address_space(3))) uint32_t*)l, 16, 0, 0);
}

// ---------------- transpose + f32 -> bf16 convert (weights, once) -------------
__global__ __launch_bounds__(256) void transpose_kernel(
    const float* __restrict__ in, short* __restrict__ out, int R, int C)
{
    __shared__ float tile[32][33];
    const int bx = blockIdx.x * 32, by = blockIdx.y * 32;
    const int tx = threadIdx.x & 31, ty = threadIdx.x >> 5;  // 32 x 8
#pragma unroll
    for (int i = 0; i < 32; i += 8)
        tile[ty + i][tx] = in[(size_t)(by + ty + i) * C + bx + tx];
    __syncthreads();
#pragma unroll
    for (int i = 0; i < 32; i += 8)
        out[(size_t)(bx + ty + i) * R + by + tx] = f2bf(tile[tx][ty + i]);
}

// ---------------- layernorm: f32 in -> bf16 out --------------------------------
__global__ __launch_bounds__(256) void ln_kernel(
    const float* __restrict__ x, const float* __restrict__ g,
    const float* __restrict__ bta, short* __restrict__ out)
{
    __shared__ float sm[8];
    const int row = blockIdx.x;
    const int t = threadIdx.x;
    const float4 v = ((const float4*)(x + (size_t)row * D_))[t];
    float s1 = v.x + v.y + v.z + v.w;
    float s2 = v.x * v.x + v.y * v.y + v.z * v.z + v.w * v.w;
#pragma unroll
    for (int off = 1; off < 64; off <<= 1) {
        s1 += __shfl_xor(s1, off);
        s2 += __shfl_xor(s2, off);
    }
    if ((t & 63) == 0) { sm[t >> 6] = s1; sm[4 + (t >> 6)] = s2; }
    __syncthreads();
    s1 = sm[0] + sm[1] + sm[2] + sm[3];
    s2 = sm[4] + sm[5] + sm[6] + sm[7];
    const float mu  = s1 * (1.f / D_);
    const float var = s2 * (1.f / D_) - mu * mu;
    const float rs  = rsqrtf(var + EPS_);
    const float4 gv = ((const float4*)g)[t];
    const float4 bv = ((const float4*)bta)[t];
    s16x4 o;
    o[0] = f2bf((v.x - mu) * rs * gv.x + bv.x);
    o[1] = f2bf((v.y - mu) * rs * gv.y + bv.y);
    o[2] = f2bf((v.z - mu) * rs * gv.z + bv.z);
    o[3] = f2bf((v.w - mu) * rs * gv.w + bv.w);
    *(s16x4*)(out + (size_t)row * D_ + t * 4) = o;
}

// ---------------- GEMM: C[M,N] = A[M,K](bf16) @ Bt[N,K]^T (bf16) + epilogue ----
// MODE 0: out bf16 = acc + bias
// MODE 1: out bf16 = relu(acc + bias)
// MODE 2: out f32  = acc + bias + res
template <int MODE>
__global__ __launch_bounds__(256) void gemm_kernel(
    const short* __restrict__ A, const short* __restrict__ Bt,
    const float* __restrict__ bias, const float* __restrict__ res,
    void* __restrict__ out, int M, int N, int K)
{
    __shared__ short As[128 * 32];
    __shared__ short Bs[128 * 32];
    const int m0 = blockIdx.y * 128;
    const int n0 = blockIdx.x * 128;
    const int tid = threadIdx.x;
    const int w = tid >> 6, l = tid & 63;
    const int wm = w >> 1, wn = w & 1;
    const int lg = l >> 4, li = l & 15;

    f32x4 acc[4][4] = {};

    for (int k0 = 0; k0 < K; k0 += 32) {
        __syncthreads();
#pragma unroll
        for (int i = 0; i < 2; ++i) {
            const int slot = w * 2 + i;            // 0..7
            const int cid = slot * 64 + l;         // 0..511
            const int row = cid >> 2, ch = cid & 3;
            gload_lds16(A + (size_t)(m0 + row) * K + k0 + ch * 8, &As[slot * 512]);
            gload_lds16(Bt + (size_t)(n0 + row) * K + k0 + ch * 8, &Bs[slot * 512]);
        }
        __syncthreads();
        s16x8 af[4], bf[4];
#pragma unroll
        for (int m = 0; m < 4; ++m)
            af[m] = *(const s16x8*)&As[(wm * 64 + m * 16 + li) * 32 + lg * 8];
#pragma unroll
        for (int n = 0; n < 4; ++n)
            bf[n] = *(const s16x8*)&Bs[(wn * 64 + n * 16 + li) * 32 + lg * 8];
#pragma unroll
        for (int m = 0; m < 4; ++m)
#pragma unroll
            for (int n = 0; n < 4; ++n)
                acc[m][n] = __builtin_amdgcn_mfma_f32_16x16x32_bf16(
                    af[m], bf[n], acc[m][n], 0, 0, 0);
    }

#pragma unroll
    for (int m = 0; m < 4; ++m) {
#pragma unroll
        for (int n = 0; n < 4; ++n) {
            const int col = n0 + wn * 64 + n * 16 + li;
            const float bv = bias[col];
#pragma unroll
            for (int r = 0; r < 4; ++r) {
                const int row = m0 + wm * 64 + m * 16 + lg * 4 + r;
                float v = acc[m][n][r] + bv;
                if (MODE == 1) v = v > 0.f ? v : 0.f;
                if (MODE == 2) {
                    float* o = (float*)out;
                    o[(size_t)row * N + col] = v + res[(size_t)row * N + col];
                } else {
                    short* o = (short*)out;
                    o[(size_t)row * N + col] = f2bf(v);
                }
            }
        }
    }
}

// ---------------- flash attention (causal), bf16 in/out -------------------------
// grid (L/64, H, B); 4 waves; wave w handles 16 q-rows; K/V tiles of 32.
__global__ __launch_bounds__(256) void attn_kernel(
    const short* __restrict__ Q, const short* __restrict__ K,
    const short* __restrict__ V, short* __restrict__ O)
{
    __shared__ short Ks[32 * 72];      // K tile, padded rows (144 B) -> ~2-way
    __shared__ short Vt[64 * 48];      // V tile transposed [dh][kv], 96 B rows
    __shared__ short Ps[4][16 * 40];   // per-wave P [16 q][32 kv], 80 B rows

    const int qblk = blockIdx.x, h = blockIdx.y, b = blockIdx.z;
    const int tid = threadIdx.x;
    const int w = tid >> 6, l = tid & 63;
    const int lg = l >> 4, li = l & 15;
    const size_t head = ((size_t)b * L_) * D_ + (size_t)h * DH_;
    const int q0 = qblk * 64;
    const int qw = q0 + w * 16;

    s16x8 qf[2];
    {
        const short* qr = Q + head + (size_t)(qw + li) * D_;
        qf[0] = *(const s16x8*)(qr + lg * 8);
        qf[1] = *(const s16x8*)(qr + 32 + lg * 8);
    }

    float m_r[4], l_r[4];
    f32x4 oacc[4] = {};
#pragma unroll
    for (int r = 0; r < 4; ++r) { m_r[r] = -1e30f; l_r[r] = 0.f; }

    const int kv_end = q0 + 64;
    const int kvr = tid >> 3, ch = tid & 7;

    for (int kv0 = 0; kv0 < kv_end; kv0 += 32) {
        __syncthreads();
        {   // stage K (row-major padded) and V (transposed)
            const short* ksrc = K + head + (size_t)(kv0 + kvr) * D_ + ch * 8;
            *(s16x8*)&Ks[kvr * 72 + ch * 8] = *(const s16x8*)ksrc;
            const s16x8 vv = *(const s16x8*)(V + head + (size_t)(kv0 + kvr) * D_ + ch * 8);
#pragma unroll
            for (int j = 0; j < 8; ++j) Vt[(ch * 8 + j) * 48 + kvr] = vv[j];
        }
        __syncthreads();

        f32x4 s[2];
#pragma unroll
        for (int half = 0; half < 2; ++half) {
            const s16x8 kf0 = *(const s16x8*)&Ks[(half * 16 + li) * 72 + lg * 8];
            const s16x8 kf1 = *(const s16x8*)&Ks[(half * 16 + li) * 72 + 32 + lg * 8];
            f32x4 c = {0.f, 0.f, 0.f, 0.f};
            c = __builtin_amdgcn_mfma_f32_16x16x32_bf16(qf[0], kf0, c, 0, 0, 0);
            c = __builtin_amdgcn_mfma_f32_16x16x32_bf16(qf[1], kf1, c, 0, 0, 0);
            s[half] = c;
        }

        float p[2][4], fac[4];
#pragma unroll
        for (int r = 0; r < 4; ++r) {
            const int qrow = qw + lg * 4 + r;
            float a0 = (kv0 + li)      <= qrow ? s[0][r] * 0.125f : -1e30f;
            float a1 = (kv0 + 16 + li) <= qrow ? s[1][r] * 0.125f : -1e30f;
            float mx = fmaxf(a0, a1);
#pragma unroll
            for (int off = 1; off < 16; off <<= 1)
                mx = fmaxf(mx, __shfl_xor(mx, off));
            const float mn = fmaxf(m_r[r], mx);
            fac[r] = __expf(m_r[r] - mn);
            m_r[r] = mn;
            const float p0 = __expf(a0 - mn);
            const float p1 = __expf(a1 - mn);
            p[0][r] = p0; p[1][r] = p1;
            float rs = p0 + p1;
#pragma unroll
            for (int off = 1; off < 16; off <<= 1)
                rs += __shfl_xor(rs, off);
            l_r[r] = l_r[r] * fac[r] + rs;
        }
#pragma unroll
        for (int d = 0; d < 4; ++d)
#pragma unroll
            for (int r = 0; r < 4; ++r)
                oacc[d][r] *= fac[r];

        short* pw = &Ps[w][0];
#pragma unroll
        for (int half = 0; half < 2; ++half)
#pragma unroll
            for (int r = 0; r < 4; ++r)
                pw[(lg * 4 + r) * 40 + half * 16 + li] = f2bf(p[half][r]);

        asm volatile("s_waitcnt lgkmcnt(0)" ::: "memory");

        const s16x8 pf = *(const s16x8*)&pw[li * 40 + lg * 8];
#pragma unroll
        for (int d = 0; d < 4; ++d) {
            const s16x8 vf = *(const s16x8*)&Vt[(d * 16 + li) * 48 + lg * 8];
            oacc[d] = __builtin_amdgcn_mfma_f32_16x16x32_bf16(pf, vf, oacc[d], 0, 0, 0);
        }
    }

#pragma unroll
    for (int r = 0; r < 4; ++r) {
        const float inv = 1.f / l_r[r];
#pragma unroll
        for (int d = 0; d < 4; ++d)
            O[head + (size_t)(qw + lg * 4 + r) * D_ + d * 16 + li] =
                f2bf(oacc[d][r] * inv);
    }
}

// ---------------- launch --------------------------------------------------------
extern "C" void kernel_launch(void* const* d_in, const int* in_sizes, int n_in,
                              void* d_out, int out_size, void* d_ws, size_t ws_size,
                              hipStream_t stream)
{
    const float* X   = (const float*)d_in[0];
    const float* WQ  = (const float*)d_in[1];
    const float* bQ  = (const float*)d_in[2];
    const float* WK  = (const float*)d_in[3];
    const float* bK  = (const float*)d_in[4];
    const float* WV  = (const float*)d_in[5];
    const float* bV  = (const float*)d_in[6];
    const float* WO  = (const float*)d_in[7];
    const float* bO  = (const float*)d_in[8];
    const float* W1  = (const float*)d_in[9];
    const float* b1  = (const float*)d_in[10];
    const float* W2  = (const float*)d_in[11];
    const float* b2  = (const float*)d_in[12];
    const float* g1  = (const float*)d_in[13];
    const float* be1 = (const float*)d_in[14];
    const float* g2  = (const float*)d_in[15];
    const float* be2 = (const float*)d_in[16];
    float* out = (float*)d_out;

    char* ws = (char*)d_ws;
    const size_t MB = 1u << 20;
    short* WQt = (short*)(ws + 0 * MB);    // [1024][1024]
    short* WKt = (short*)(ws + 2 * MB);
    short* WVt = (short*)(ws + 4 * MB);
    short* WOt = (short*)(ws + 6 * MB);
    short* W1t = (short*)(ws + 8 * MB);    // [4096][1024]
    short* W2t = (short*)(ws + 16 * MB);   // [1024][4096]
    short* Xn  = (short*)(ws + 24 * MB);   // [8192][1024] (LN1, reused for LN2)
    short* Qb  = (short*)(ws + 40 * MB);   // [8192][1024]
    short* Kb  = (short*)(ws + 56 * MB);
    short* Vb  = (short*)(ws + 72 * MB);
    short* AV  = (short*)(ws + 88 * MB);
    short* H1  = (short*)(ws + 40 * MB);   // [8192][4096], reuses Q/K/V/AV

    const dim3 tb(256);

    transpose_kernel<<<dim3(32, 32), tb, 0, stream>>>(WQ, WQt, 1024, 1024);
    transpose_kernel<<<dim3(32, 32), tb, 0, stream>>>(WK, WKt, 1024, 1024);
    transpose_kernel<<<dim3(32, 32), tb, 0, stream>>>(WV, WVt, 1024, 1024);
    transpose_kernel<<<dim3(32, 32), tb, 0, stream>>>(WO, WOt, 1024, 1024);
    transpose_kernel<<<dim3(128, 32), tb, 0, stream>>>(W1, W1t, 1024, 4096);
    transpose_kernel<<<dim3(32, 128), tb, 0, stream>>>(W2, W2t, 4096, 1024);

    ln_kernel<<<8192, tb, 0, stream>>>(X, g1, be1, Xn);

    gemm_kernel<0><<<dim3(8, 64), tb, 0, stream>>>(Xn, WQt, bQ, nullptr, Qb, 8192, 1024, 1024);
    gemm_kernel<0><<<dim3(8, 64), tb, 0, stream>>>(Xn, WKt, bK, nullptr, Kb, 8192, 1024, 1024);
    gemm_kernel<0><<<dim3(8, 64), tb, 0, stream>>>(Xn, WVt, bV, nullptr, Vb, 8192, 1024, 1024);

    attn_kernel<<<dim3(L_ / 64, H_, B_), tb, 0, stream>>>(Qb, Kb, Vb, AV);

    gemm_kernel<2><<<dim3(8, 64), tb, 0, stream>>>(AV, WOt, bO, X, out, 8192, 1024, 1024);

    ln_kernel<<<8192, tb, 0, stream>>>(out, g2, be2, Xn);

    gemm_kernel<1><<<dim3(32, 64), tb, 0, stream>>>(Xn, W1t, b1, nullptr, H1, 8192, 4096, 1024);
    gemm_kernel<2><<<dim3(8, 64), tb, 0, stream>>>(H1, W2t, b2, out, out, 8192, 1024, 4096);
}